// Round 4
// baseline (284.280 us; speedup 1.0000x reference)
//
#include <hip/hip_runtime.h>

// MultiscaleLLN: out = x / (gauss13x13(lum(x)) / dens + eps), 4 pyramid levels.
// R4: 64x32 tiles, register-resident interior RGB (no re-read), col-conv in
// owner threads via ds_read_b128, NON-TEMPORAL output stores so the 134 MB
// output stream doesn't evict the 134 MB input from the 256 MB L3 (R3 showed
// FETCH=194MB = input + 60MB of L3-eviction misses).

typedef float f4 __attribute__((ext_vector_type(4)));

#define NPIX   87040
#define EPSV   1e-3f
#define WSUM   0.9999f      // 0.2989 + 0.587 + 0.114
#define TW     64
#define TH     32
#define RAD    6
#define LW     80           // loaded px/row: [tx0-8, tx0+72)
#define LH     44           // loaded rows:   [ty0-6, ty0+38)

// 1D Gaussian taps G1[d+6] = exp(-d^2/18)/sqrt(18*pi), d = -6..6
__device__ __constant__ float G1[13] = {
    0.01799699f, 0.03315904f, 0.05467002f, 0.08065689f, 0.10648267f,
    0.12579441f, 0.13298076f, 0.12579441f, 0.10648267f, 0.08065689f,
    0.05467002f, 0.03315904f, 0.01799699f
};
// prefix sums PRE[i] = sum_{j<i} G1[j]
__device__ __constant__ float PRE[14] = {
    0.00000000f, 0.01799699f, 0.05115603f, 0.10582605f, 0.18648294f,
    0.29296561f, 0.41876002f, 0.55174078f, 0.67753519f, 0.78401786f,
    0.86467475f, 0.91934477f, 0.95250381f, 0.97050080f
};

__global__ __launch_bounds__(256, 6)
void mslln_kernel(const float* __restrict__ x, float* __restrict__ out) {
    __shared__ float s_lum[LH][LW];   // 44x80 = 14.1 KB
    __shared__ float s_rc[LH][TW];    // 44x64 = 11.0 KB  (total 25.1 KB -> 6 blk/CU)

    const int bid = blockIdx.x;
    const int t   = threadIdx.x;

    // block -> (level, image, tile); tiles are 64x32 outputs
    // L0: 256x256 -> 4x8=32 tiles *128 = 4096   [0,4096)
    // L1: 128x128 -> 2x4=8  tiles *128 = 1024   [4096,5120)
    // L2:  64x64  -> 1x2=2  tiles *128 =  256   [5120,5376)
    // L3:  32x32  -> 1      tile  *128 =  128   [5376,5504)
    int img, tl, txlog, h, off;
    if (bid < 4096)      { img = bid >> 5;               tl = bid & 31; txlog = 2; h = 256; off = 0;     }
    else if (bid < 5120) { int r = bid - 4096; img = r >> 3; tl = r & 7; txlog = 1; h = 128; off = 65536; }
    else if (bid < 5376) { int r = bid - 5120; img = r >> 1; tl = r & 1; txlog = 0; h = 64;  off = 81920; }
    else                 { img = bid - 5376;   tl = 0;       txlog = 0; h = 32;  off = 86016; }
    const int w   = h;
    const int tx0 = (tl & ((1 << txlog) - 1)) << 6;  // *64
    const int ty0 = (tl >> txlog) << 5;              // *32

    const float* __restrict__ xb = x   + (size_t)img * (NPIX * 3) + (size_t)off * 3;
    float*       __restrict__ ob = out + (size_t)img * (NPIX * 3) + (size_t)off * 3;

    // interior ownership: thread owns 4-px groups (row ogr, ogr+16; cols ogx0..+3)
    const int ogr  = t >> 4;           // 0..15
    const int ogc  = t & 15;           // 0..15
    const int ogx0 = tx0 + (ogc << 2);
    f4 rgb[2][3];

    // ---- Phase 1a: interior -> registers, lum -> LDS ----
#pragma unroll
    for (int g = 0; g < 2; g++) {
        int ly = ogr + (g << 4);       // 0..31
        int gy = ty0 + ly;             // always < h by tiling
        f4 f0 = 0.f, f1 = 0.f, f2 = 0.f;
        if (ogx0 < w) {                // only false on L3 (w=32)
            const f4* p = (const f4*)(xb + ((size_t)gy * w + ogx0) * 3);
            f0 = p[0]; f1 = p[1]; f2 = p[2];
        }
        rgb[g][0] = f0; rgb[g][1] = f1; rgb[g][2] = f2;
        f4 l;
        l.x = 0.2989f*f0.x + 0.587f*f0.y + 0.114f*f0.z;
        l.y = 0.2989f*f0.w + 0.587f*f1.x + 0.114f*f1.y;
        l.z = 0.2989f*f1.z + 0.587f*f1.w + 0.114f*f2.x;
        l.w = 0.2989f*f2.y + 0.587f*f2.z + 0.114f*f2.w;
        *(f4*)&s_lum[ly + RAD][(ogc << 2) + 8] = l;
    }

    // ---- Phase 1b: halo groups (44x20=880 groups; 16x32=512 interior skipped) ----
#pragma unroll
    for (int k = 0; k < 4; k++) {
        unsigned i = (unsigned)t + k * 256u;
        if (i < 880u) {
            int gr = (int)(i / 20u);           // 0..43
            int gc = (int)(i - (unsigned)gr * 20u); // 0..19
            bool interior = (gr >= RAD) && (gr < RAD + TH) && (gc >= 2) && (gc < 18);
            if (!interior) {
                int gy  = ty0 + gr - RAD;
                int gx0 = tx0 + (gc << 2) - 8;     // float index 3*gx0 is 16B-aligned
                f4 f0 = 0.f, f1 = 0.f, f2 = 0.f;
                if (gy >= 0 && gy < h) {
                    if (gx0 >= 0 && gx0 + 3 < w) {
                        const f4* p = (const f4*)(xb + ((size_t)gy * w + gx0) * 3);
                        f0 = p[0]; f1 = p[1]; f2 = p[2];
                    } else {
                        float v[12];
#pragma unroll
                        for (int c = 0; c < 12; c++) v[c] = 0.f;
#pragma unroll
                        for (int c = 0; c < 4; c++) {
                            int gx = gx0 + c;
                            if (gx >= 0 && gx < w) {
                                const float* s = xb + ((size_t)gy * w + gx) * 3;
                                v[3*c] = s[0]; v[3*c+1] = s[1]; v[3*c+2] = s[2];
                            }
                        }
                        f0 = (f4){v[0], v[1], v[2],  v[3]};
                        f1 = (f4){v[4], v[5], v[6],  v[7]};
                        f2 = (f4){v[8], v[9], v[10], v[11]};
                    }
                }
                f4 l;
                l.x = 0.2989f*f0.x + 0.587f*f0.y + 0.114f*f0.z;
                l.y = 0.2989f*f0.w + 0.587f*f1.x + 0.114f*f1.y;
                l.z = 0.2989f*f1.z + 0.587f*f1.w + 0.114f*f2.x;
                l.w = 0.2989f*f2.y + 0.587f*f2.z + 0.114f*f2.w;
                *(f4*)&s_lum[gr][gc << 2] = l;
            }
        }
    }
    __syncthreads();

    // ---- Phase 2: row conv, 44x64 = 2816 = 11*256 exact ----
    // s_lum[r][c'] holds px gx = tx0 + c' - 8; output col c taps c+2..c+14
#pragma unroll
    for (int k = 0; k < 11; k++) {
        int i = t + k * 256;
        int r = i >> 6, c = i & 63;
        float s = 0.f;
#pragma unroll
        for (int j = 0; j < 13; j++) s += s_lum[r][c + 2 + j] * G1[j];
        s_rc[r][c] = s;
    }
    __syncthreads();

    // ---- Phase 3: col conv (b128 LDS reads) + analytic dens + NT store ----
#pragma unroll
    for (int g = 0; g < 2; g++) {
        int ly = ogr + (g << 4);
        int gy = ty0 + ly;
        if (ogx0 >= w) continue;       // only on L3
        f4 acc = 0.f;
#pragma unroll
        for (int j = 0; j < 13; j++) {
            f4 v = *(const f4*)&s_rc[ly + j][ogc << 2];
            acc += v * G1[j];
        }
        int ylo = min(RAD, gy), yhi = min(RAD, h - 1 - gy);
        float Sy = PRE[RAD + yhi + 1] - PRE[RAD - ylo];
        f4 sc;
#pragma unroll
        for (int c = 0; c < 4; c++) {
            int gx  = ogx0 + c;
            int xlo = min(RAD, gx), xhi = min(RAD, w - 1 - gx);
            float Sx   = PRE[RAD + xhi + 1] - PRE[RAD - xlo];
            float dens = WSUM * Sy * Sx;
            sc[c] = 1.0f / (acc[c] / dens + EPSV);
        }
        f4 o0 = rgb[g][0], o1 = rgb[g][1], o2 = rgb[g][2];
        o0.x *= sc.x; o0.y *= sc.x; o0.z *= sc.x; o0.w *= sc.y;
        o1.x *= sc.y; o1.y *= sc.y; o1.z *= sc.z; o1.w *= sc.z;
        o2.x *= sc.z; o2.y *= sc.w; o2.z *= sc.w; o2.w *= sc.w;
        f4* q = (f4*)(ob + ((size_t)gy * w + ogx0) * 3);
        __builtin_nontemporal_store(o0, q);
        __builtin_nontemporal_store(o1, q + 1);
        __builtin_nontemporal_store(o2, q + 2);
    }
}

extern "C" void kernel_launch(void* const* d_in, const int* in_sizes, int n_in,
                              void* d_out, int out_size, void* d_ws, size_t ws_size,
                              hipStream_t stream) {
    const float* x = (const float*)d_in[0];
    float* out = (float*)d_out;
    mslln_kernel<<<5504, 256, 0, stream>>>(x, out);
}